// Round 16
// baseline (3708.681 us; speedup 1.0000x reference)
//
#include <hip/hip_runtime.h>

// LSTM fused kernel for MI355X (gfx950) — round 16: NO LDS A-tile.
// r12/r15's transposed MFMA means the activation operand is, per lane,
// 16 contiguous bytes of a h/x row — loadable DIRECTLY from global (L2).
// Staging phase and syncA deleted: each wave issues 10 independent
// global_load_dwordx4 into bv[0..9] and runs the K-loop; compiler
// interleaves vmcnt waits with MFMAs. kh==3's 8 x-chunks are issued
// BEFORE the flag spin (flag-independent prefetch).
// 256 blocks x 512 threads (8 waves, 2/SIMD). Group = measured XCD; 32
// batch rows split into tiles A/B (16 rows) alternated per slot.
// Wave (hgrp=wv&1, kh=wv>>1); z^T = W·[h|x]^T; lane holds all 4 gates of
// one (row,hcol); cross-kh reduce via single 32KB zbuf; c in regs.
// 2 syncthreads/slot (B: zbuf->gates, C: h-store drain -> flag).
// Sync: relaxed agent flags + per-wave buffer_inv sc0 acquire, early-poll,
// deferred inv; threadfence fallback; guards 1<<18.
// Workspace: WT fp16 [4096][1280] @0, WphT @10485760,
// hbuf [2][256][1024] @11010048, lg @12058624, cnt @12320768, tick @12322816,
// xh fp16 [256][512][256] @16777216 (only if ws_size >= 83886080).

typedef _Float16 f16;
typedef _Float16 f16x8 __attribute__((ext_vector_type(8)));
typedef _Float16 f16x4 __attribute__((ext_vector_type(4)));
typedef float f32x4 __attribute__((ext_vector_type(4)));
typedef unsigned int u32;

#define WS_WT    0
#define WS_WPHT  10485760
#define WS_HBUF  11010048
#define WS_LG    12058624
#define WS_CNT   12320768
#define WS_TICK  12322816
#define WS_XH    16777216
#define WS_XH_END 83886080

// LDS: zbuf [kh4][512 x 16B] @0 (32 KB, slot16 = (row*32+hcol) ^ (row&7));
// bcast @32768.
#define ZB    0u
#define BCAST 32768

__device__ __forceinline__ float sigm(float v) { return 1.0f / (1.0f + __expf(-v)); }
__device__ __forceinline__ float tanhfast(float v) {
  float t = __expf(-2.0f * fabsf(v));
  float r = (1.0f - t) / (1.0f + t);
  return v < 0.0f ? -r : r;
}

// ---------- prep: WT[n][k], n=gate*1024+j (z-col), k<1024 -> Wh[k][j], else Wx[k-1024][j]
__global__ __launch_bounds__(256) void prep_wt(
    const float* __restrict__ Wgh, const float* __restrict__ Wih,
    const float* __restrict__ Wfh, const float* __restrict__ Woh,
    const float* __restrict__ Wgx, const float* __restrict__ Wix,
    const float* __restrict__ Wfx, const float* __restrict__ Wox,
    f16* __restrict__ WT)
{
  __shared__ float tile[32][33];
  int bid = blockIdx.x;
  int gate = bid / 1280;
  int rem  = bid % 1280;
  int jt = rem / 40, kt = rem % 40;
  const float* srcH = (gate==0)?Wgh:(gate==1)?Wih:(gate==2)?Wfh:Woh;
  const float* srcX = (gate==0)?Wgx:(gate==1)?Wix:(gate==2)?Wfx:Wox;
  const float* src = (kt < 32) ? (srcH + (size_t)(kt*32)*1024)
                               : (srcX + (size_t)(kt*32 - 1024)*1024);
  int t = threadIdx.x;
  {
    int jl = t & 31, kg = t >> 5;
#pragma unroll
    for (int it = 0; it < 4; ++it) {
      int kl = kg + it*8;
      tile[kl][jl] = src[(size_t)kl*1024 + jt*32 + jl];
    }
  }
  __syncthreads();
  {
    int kl = t & 31, jg = t >> 5;
#pragma unroll
    for (int it = 0; it < 4; ++it) {
      int jl2 = jg + it*8;
      WT[(size_t)(gate*1024 + jt*32 + jl2)*1280 + kt*32 + kl] = (f16)tile[kl][jl2];
    }
  }
}

// ---------- prep: WphT[oc][k] = W_ph[k][oc], fp16
__global__ __launch_bounds__(256) void prep_wph(const float* __restrict__ Wph,
                                                f16* __restrict__ WphT)
{
  __shared__ float tile[32][33];
  int bid = blockIdx.x;
  int jt = bid & 7, kt = bid >> 3;
  int t = threadIdx.x;
  {
    int jl = t & 31, kg = t >> 5;
#pragma unroll
    for (int it = 0; it < 4; ++it) {
      int kl = kg + it*8;
      tile[kl][jl] = Wph[(size_t)(kt*32 + kl)*256 + jt*32 + jl];
    }
  }
  __syncthreads();
  {
    int kl = t & 31, jg = t >> 5;
#pragma unroll
    for (int it = 0; it < 4; ++it) {
      int jl2 = jg + it*8;
      WphT[(size_t)(jt*32 + jl2)*1024 + kt*32 + kl] = (f16)tile[kl][jl2];
    }
  }
}

// ---------- prep: x f32 -> f16 (33.5M elems, 16/thread)
__global__ __launch_bounds__(256) void prep_x16(const float* __restrict__ x,
                                                f16* __restrict__ xh)
{
  size_t i = ((size_t)blockIdx.x*256 + threadIdx.x) * 16;
  const float4* src = (const float4*)(x + i);
  f16x4* dst = (f16x4*)(xh + i);
#pragma unroll
  for (int j = 0; j < 4; ++j) {
    float4 v = src[j];
    f16x4 h; h[0]=(f16)v.x; h[1]=(f16)v.y; h[2]=(f16)v.z; h[3]=(f16)v.w;
    dst[j] = h;
  }
}

// ---------- main persistent LSTM kernel
__global__ __launch_bounds__(512, 2) void lstm_main(
    const float* __restrict__ x, const f16* __restrict__ xh, int use_xh,
    const f16* __restrict__ WT, const f16* __restrict__ WphT,
    f16* __restrict__ hbuf,
    const float* __restrict__ bgp, const float* __restrict__ bip,
    const float* __restrict__ bfp, const float* __restrict__ bop,
    const float* __restrict__ bpp, float* __restrict__ lg,
    u32* __restrict__ cnt, u32* __restrict__ tick, float* __restrict__ out)
{
  __shared__ __align__(16) char smem[32784];
  const int tid  = threadIdx.x;
  const int lane = tid & 63;
  const int wv   = tid >> 6;
  const int hgrp = wv & 1;         // h-col half (16 cols)
  const int kh   = wv >> 1;        // K quarter (320)
  const int l15 = lane & 15, l4 = lane >> 4;

  // ---- measure XCD, take ticket on per-XCD counter
  u32 myxcd;
  asm volatile("s_getreg_b32 %0, hwreg(HW_REG_XCC_ID)" : "=s"(myxcd));
  myxcd &= 7u;
  if (tid == 0) {
    u32 t = __hip_atomic_fetch_add(tick + myxcd, 1u,
                                   __ATOMIC_RELAXED, __HIP_MEMORY_SCOPE_AGENT);
    *(volatile u32*)(smem + BCAST) = t;
  }
  if (wv == 0) {
    u32 v = 0;
    int guard = 0;
    for (;;) {
      v = (lane < 8) ? __hip_atomic_load(tick + lane, __ATOMIC_RELAXED,
                                         __HIP_MEMORY_SCOPE_AGENT) : 0u;
      u32 sum = v;
      sum += __shfl_xor(sum, 1);
      sum += __shfl_xor(sum, 2);
      sum += __shfl_xor(sum, 4);
      if (__shfl(sum, 0) == 256u) break;
      __builtin_amdgcn_s_sleep(1);
      if (++guard > (1 << 20)) break;
    }
    int even = __all((lane < 8) ? (v == 32u) : 1);
    if (lane == 0) *(volatile u32*)(smem + BCAST + 4) = (u32)even;
  }
  __syncthreads();
  const bool xloc = (*(volatile u32*)(smem + BCAST + 4)) != 0u;
  const u32 myticket = *(volatile u32*)(smem + BCAST);
  const int xg = xloc ? (int)myxcd    : (blockIdx.x & 7);   // batch-tile group
  const int cg = xloc ? (int)myticket : (blockIdx.x >> 3);  // column slice 0..31
  u32* flg = cnt + xg*64;           // [tileA flags 0..31][tileB flags 32..63]

  // ---- weight-stationary A-op fragments: [10 kk][4 frags] = 160 regs.
  // Lane l15 = m = hcolsub*4 + gate (gate-minor interleave).
  f16x8 Breg[10][4];
  {
    const int gate = l15 & 3, hsub = l15 >> 2;
#pragma unroll
    for (int f = 0; f < 4; ++f) {
      const int n = gate*1024 + cg*32 + hgrp*16 + f*4 + hsub;
      const f16* wb = WT + (size_t)n*1280 + kh*320 + l4*8;
#pragma unroll
      for (int kk = 0; kk < 10; ++kk) {
        Breg[kk][f] = *(const f16x8*)(wb + kk*32);
        asm volatile("" : "+v"(Breg[kk][f]));   // pin: no remat
      }
    }
  }

  // per-thread bias (gates phase handles hcol = tid&31)
  const int bcol = cg*32 + (tid & 31);
  const float bgr = bgp[bcol], bir = bip[bcol], bfr = bfp[bcol], bor = bop[bcol];

  // B-op row for this lane (batch row) changes with tile T
  // c state in registers (gates thread owns (row=tid>>5, hcol=tid&31))
  float cA = 0.0f, cB = 0.0f;

  u32 pre = 0xFFFFFFFFu;
  bool preOK = false;

#pragma unroll 1
  for (int slot = 0; slot < 1024; ++slot) {
    const int T = slot & 1, s = slot >> 1;
    u32* flgT = flg + T*32;
    const int rowB = xg*32 + T*16 + l15;     // this lane's batch row

    f16x8 bv0, bv1, bv2, bv3, bv4, bv5, bv6, bv7, bv8, bv9;
    // ---- x chunks (kh==3, kk=2..9): flag-independent, issue BEFORE spin
    if (kh == 3) {
      if (use_xh) {
        const char* xb = (const char*)(xh + (size_t)rowB*131072 + (size_t)s*256)
                       + l4*16;
        bv2 = *(const f16x8*)(xb       );
        bv3 = *(const f16x8*)(xb +  64);
        bv4 = *(const f16x8*)(xb + 128);
        bv5 = *(const f16x8*)(xb + 192);
        bv6 = *(const f16x8*)(xb + 256);
        bv7 = *(const f16x8*)(xb + 320);
        bv8 = *(const f16x8*)(xb + 384);
        bv9 = *(const f16x8*)(xb + 448);
      } else {
        const float* xf = x + (size_t)rowB*131072 + (size_t)s*256 + l4*8;
#pragma unroll
        for (int kk = 2; kk < 10; ++kk) {
          float4 a = *(const float4*)(xf + (kk-2)*32);
          float4 b = *(const float4*)(xf + (kk-2)*32 + 4);
          f16x8 hv;
          hv[0]=(f16)a.x; hv[1]=(f16)a.y; hv[2]=(f16)a.z; hv[3]=(f16)a.w;
          hv[4]=(f16)b.x; hv[5]=(f16)b.y; hv[6]=(f16)b.z; hv[7]=(f16)b.w;
          switch (kk) {
            case 2: bv2=hv; break; case 3: bv3=hv; break;
            case 4: bv4=hv; break; case 5: bv5=hv; break;
            case 6: bv6=hv; break; case 7: bv7=hv; break;
            case 8: bv8=hv; break; default: bv9=hv; break;
          }
        }
      }
    }
    // ---- per-wave barrier: only if this wave's early-poll didn't confirm
    if (s > 0 && !preOK) {
      const u32 tgt = (u32)s;
      u32 v = tgt;
      int guard = 0;
      for (;;) {
        if (lane < 32)
          v = __hip_atomic_load(flgT + lane, __ATOMIC_RELAXED,
                                __HIP_MEMORY_SCOPE_AGENT);
        if (__all(v >= tgt)) break;
        __builtin_amdgcn_s_sleep(1);
        if (++guard > (1 << 18)) break;
      }
      if (lane == 0) {
        if (xloc) { asm volatile("buffer_inv sc0\n\ts_waitcnt vmcnt(0)" ::: "memory"); }
        else      { __threadfence(); }
      }
    }
    // ---- h chunks direct from L2 (post-inv)
    {
      const char* hb = (const char*)(hbuf + (size_t)(s & 1)*262144
                                     + (size_t)rowB*1024) + kh*640 + l4*16;
      if (kh < 3) {
        bv0 = *(const f16x8*)(hb       );
        bv1 = *(const f16x8*)(hb +  64);
        bv2 = *(const f16x8*)(hb + 128);
        bv3 = *(const f16x8*)(hb + 192);
        bv4 = *(const f16x8*)(hb + 256);
        bv5 = *(const f16x8*)(hb + 320);
        bv6 = *(const f16x8*)(hb + 384);
        bv7 = *(const f16x8*)(hb + 448);
        bv8 = *(const f16x8*)(hb + 512);
        bv9 = *(const f16x8*)(hb + 576);
      } else {
        bv0 = *(const f16x8*)(hb      );
        bv1 = *(const f16x8*)(hb + 64);
      }
    }
    // ---- K loop: K/4 per wave; one bv feeds 4 gate-frags
    f32x4 acc0 = {}, acc1 = {}, acc2 = {}, acc3 = {};
#pragma unroll
    for (int kk = 0; kk < 10; ++kk) {
      f16x8 av = (kk==0)?bv0:(kk==1)?bv1:(kk==2)?bv2:(kk==3)?bv3:(kk==4)?bv4:
                 (kk==5)?bv5:(kk==6)?bv6:(kk==7)?bv7:(kk==8)?bv8:bv9;
      acc0 = __builtin_amdgcn_mfma_f32_16x16x32_f16(Breg[kk][0], av, acc0, 0, 0, 0);
      acc1 = __builtin_amdgcn_mfma_f32_16x16x32_f16(Breg[kk][1], av, acc1, 0, 0, 0);
      acc2 = __builtin_amdgcn_mfma_f32_16x16x32_f16(Breg[kk][2], av, acc2, 0, 0, 0);
      acc3 = __builtin_amdgcn_mfma_f32_16x16x32_f16(Breg[kk][3], av, acc3, 0, 0, 0);
    }
    // ---- early poll (ALL waves): next slot's flags, consumed after gates
    {
      const int nT = (slot + 1) & 1, nS = (slot + 1) >> 1;
      pre = 0xFFFFFFFFu;
      if (nS > 0 && nS < 512 && lane < 32)
        pre = __hip_atomic_load(flg + nT*32 + lane, __ATOMIC_RELAXED,
                                __HIP_MEMORY_SCOPE_AGENT);
    }
    // ---- zbuf partial write: f32x4 (4 gates) at slot16=(row*32+hcol)^(row&7)
    {
      const u32 zkh = ZB + (u32)kh*8192u;
#pragma unroll
      for (int f = 0; f < 4; ++f) {
        const u32 hcol = (u32)(hgrp*16 + f*4 + l4);
        const u32 s16 = ((u32)(l15*32) + hcol) ^ ((u32)(l15 & 7));
        f32x4 acc = (f==0)?acc0:(f==1)?acc1:(f==2)?acc2:acc3;
        *(f32x4*)(smem + zkh + s16*16u) = acc;
      }
    }
    __syncthreads();   // (B) zbuf ready
    // ---- gates: thread (row=tid>>5, hcol=tid&31), all lanes active
    {
      f16* hw = hbuf + (size_t)((s & 1) ^ 1)*262144;
      const int row = tid >> 5, hcol = tid & 31;
      const u32 s16 = ((u32)(row*32) + (u32)hcol) ^ ((u32)(row & 7));
      const u32 ro = s16*16u;
      f32x4 z0 = *(const f32x4*)(smem + ZB +        ro);
      f32x4 z1 = *(const f32x4*)(smem + ZB + 8192u  + ro);
      f32x4 z2 = *(const f32x4*)(smem + ZB + 16384u + ro);
      f32x4 z3 = *(const f32x4*)(smem + ZB + 24576u + ro);
      float zg = z0[0] + z1[0] + z2[0] + z3[0] + bgr;
      float zi = z0[1] + z1[1] + z2[1] + z3[1] + bir;
      float zf = z0[2] + z1[2] + z2[2] + z3[2] + bfr;
      float zo = z0[3] + z1[3] + z2[3] + z3[3] + bor;
      float cv = T ? cB : cA;
      float gv = tanhfast(zg);
      float iv = sigm(zi);
      float fv = sigm(zf);
      float ov = sigm(zo);
      float cn = gv*iv + cv*fv;
      if (T) cB = cn; else cA = cn;
      hw[(size_t)(xg*32 + T*16 + row)*1024 + cg*32 + hcol] = (f16)(tanhfast(cn) * ov);
    }
    // ---- preOK eval + deferred inv (per wave)
    {
      const int nS = (slot + 1) >> 1;
      bool ok = (nS >= 512) || __all(pre >= (u32)nS);
      preOK = xloc && ok;
      if (preOK && nS < 512 && lane == 0) {
        asm volatile("buffer_inv sc0\n\ts_waitcnt vmcnt(0)" ::: "memory");
      }
    }
    __syncthreads();   // (C) drains h stores + orders inv; guards zbuf reuse
    if (tid == 0) {
      if (!xloc) __threadfence();
      __hip_atomic_store(flgT + cg, (u32)(s + 1),
                         __ATOMIC_RELAXED, __HIP_MEMORY_SCOPE_AGENT);
    }
  }

  // ---- epilogue: wait both tiles at 512, logits = h @ WphT + bp
  if (wv == 0) {
    u32 v = 512u;
    int guard = 0;
    for (;;) {
      v = __hip_atomic_load(flg + lane, __ATOMIC_RELAXED,
                            __HIP_MEMORY_SCOPE_AGENT);   // lanes 0-63 = A,B
      if (__all(v >= 512u)) break;
      __builtin_amdgcn_s_sleep(1);
      if (++guard > (1 << 18)) break;
    }
    if (lane == 0) {
      if (xloc) { asm volatile("buffer_inv sc0\n\ts_waitcnt vmcnt(0)" ::: "memory"); }
      else      { __threadfence(); }
    }
  }
  __syncthreads();
  {
#pragma unroll 1
    for (int p = 0; p < 32; ++p) {
      int rowl = wv*4 + (p >> 3);
      int oc   = p & 7;
      const f16* hp = hbuf + (size_t)(xg*32 + rowl)*1024 + lane*16;  // buf 0 = h_T
      const f16* wp = WphT + (size_t)(cg*8 + oc)*1024 + lane*16;
      f16x8 h0 = *(const f16x8*)hp;
      f16x8 h1 = *(const f16x8*)(hp + 8);
      f16x8 w0 = *(const f16x8*)wp;
      f16x8 w1 = *(const f16x8*)(wp + 8);
      float sum = 0.f;
#pragma unroll
      for (int q = 0; q < 8; ++q)
        sum += (float)h0[q]*(float)w0[q] + (float)h1[q]*(float)w1[q];
#pragma unroll
      for (int d = 1; d < 64; d <<= 1) sum += __shfl_xor(sum, d);
      if (lane == 0)
        lg[(size_t)(xg*32 + rowl)*256 + cg*8 + oc] = sum + bpp[cg*8 + oc];
    }
  }
  __syncthreads();   // drain lg stores
  if (tid == 0) {
    if (!xloc) __threadfence();
    __hip_atomic_store(flg + cg, 513u, __ATOMIC_RELAXED, __HIP_MEMORY_SCOPE_AGENT);
  }
  if (wv == 0) {
    u32 v = 513u;
    int guard = 0;
    for (;;) {
      if (lane < 32)
        v = __hip_atomic_load(flg + lane, __ATOMIC_RELAXED, __HIP_MEMORY_SCOPE_AGENT);
      if (__all(v >= 513u)) break;
      __builtin_amdgcn_s_sleep(1);
      if (++guard > (1 << 18)) break;
    }
    if (lane == 0) {
      if (xloc) { asm volatile("buffer_inv sc0\n\ts_waitcnt vmcnt(0)" ::: "memory"); }
      else      { __threadfence(); }
    }
  }
  __syncthreads();
  // ---- softmax: this block handles row xg*32+cg, wave 0 only
  if (tid < 64) {
    int rowg = xg*32 + cg;
    const float* lr = lg + (size_t)rowg*256;
    float v0 = lr[tid], v1 = lr[tid+64], v2 = lr[tid+128], v3 = lr[tid+192];
    float mx = fmaxf(fmaxf(v0, v1), fmaxf(v2, v3));
#pragma unroll
    for (int d = 1; d < 64; d <<= 1) mx = fmaxf(mx, __shfl_xor(mx, d));
    float e0 = __expf(v0-mx), e1 = __expf(v1-mx), e2 = __expf(v2-mx), e3 = __expf(v3-mx);
    float sm = e0+e1+e2+e3;
#pragma unroll
    for (int d = 1; d < 64; d <<= 1) sm += __shfl_xor(sm, d);
    float inv = 1.0f / sm;
    float* orow = out + (size_t)rowg*256;
    orow[tid]      = e0*inv;
    orow[tid+64]   = e1*inv;
    orow[tid+128]  = e2*inv;
    orow[tid+192]  = e3*inv;
  }
}

extern "C" void kernel_launch(void* const* d_in, const int* in_sizes, int n_in,
                              void* d_out, int out_size, void* d_ws, size_t ws_size,
                              hipStream_t stream) {
  (void)in_sizes; (void)n_in; (void)out_size;
  const float* x   = (const float*)d_in[0];
  const float* Wgx = (const float*)d_in[1];
  const float* Wgh = (const float*)d_in[2];
  const float* bg  = (const float*)d_in[3];
  const float* Wix = (const float*)d_in[4];
  const float* Wih = (const float*)d_in[5];
  const float* bi  = (const float*)d_in[6];
  const float* Wfx = (const float*)d_in[7];
  const float* Wfh = (const float*)d_in[8];
  const float* bf  = (const float*)d_in[9];
  const float* Wox = (const float*)d_in[10];
  const float* Woh = (const float*)d_in[11];
  const float* bo  = (const float*)d_in[12];
  const float* Wph = (const float*)d_in[13];
  const float* bp  = (const float*)d_in[14];

  char* ws = (char*)d_ws;
  f16*   WT   = (f16*)(ws + WS_WT);
  f16*   WphT = (f16*)(ws + WS_WPHT);
  f16*   hbuf = (f16*)(ws + WS_HBUF);
  float* lg   = (float*)(ws + WS_LG);
  u32*   cnt  = (u32*)(ws + WS_CNT);
  u32*   tick = (u32*)(ws + WS_TICK);
  const int use_xh = (ws_size >= (size_t)WS_XH_END) ? 1 : 0;
  f16*   xh   = (f16*)(ws + WS_XH);

  // h0 = 0 (buffer 0); flags + tickets = 0 (replay-safe)
  hipMemsetAsync(hbuf, 0, 524288, stream);
  hipMemsetAsync(cnt, 0, 2048 + 64, stream);

  prep_wt<<<5120, 256, 0, stream>>>(Wgh, Wih, Wfh, Woh, Wgx, Wix, Wfx, Wox, WT);
  prep_wph<<<256, 256, 0, stream>>>(Wph, WphT);
  if (use_xh)
    prep_x16<<<8192, 256, 0, stream>>>(x, xh);
  lstm_main<<<256, 512, 0, stream>>>(x, xh, use_xh, WT, WphT, hbuf,
                                     bg, bi, bf, bo, bp,
                                     lg, cnt, tick, (float*)d_out);
}

// Round 17
// 2795.237 us; speedup vs baseline: 1.3268x; 1.3268x over previous
//
#include <hip/hip_runtime.h>

// LSTM fused kernel for MI355X (gfx950) — round 17: UN-INTERLEAVED slots.
// r15 skeleton (best 2472us) but ONE 32-row tile per group per slot:
// 512 slots instead of 1024 -> sync count + flag rounds halve; per-slot
// overhead (3 syncs + zbuf + spin, ~1.4us, slot-constant) amortizes over 2x
// work. Early-poll (issued mid-slot) + deferred inv cover flag latency.
// 256 blocks x 512 threads (8 waves, 2/SIMD). Group = measured XCD.
// Transposed MFMA: wave (hgrp=wv&1, kh=wv>>1), z^T = W·[h|x]^T, lane holds
// all 4 gates of one (row,hcol); rows 0-15 and 16-31 via 2 acc chains;
// cross-kh reduce via 64KB zbuf; c in regs (2/thread); gates all-lanes.
// 3 syncthreads/slot. Sync: relaxed agent flags + per-wave buffer_inv sc0
// acquire, early-poll, deferred inv; threadfence fallback; guards 1<<18.
// Workspace: WT fp16 [4096][1280] @0, WphT @10485760,
// hbuf [2][256][1024] @11010048, lg @12058624, cnt @12320768, tick @12322816,
// xh fp16 [256][512][256] @16777216 (only if ws_size >= 83886080).

typedef _Float16 f16;
typedef _Float16 f16x8 __attribute__((ext_vector_type(8)));
typedef _Float16 f16x4 __attribute__((ext_vector_type(4)));
typedef float f32x4 __attribute__((ext_vector_type(4)));
typedef unsigned int u32;

#define WS_WT    0
#define WS_WPHT  10485760
#define WS_HBUF  11010048
#define WS_LG    12058624
#define WS_CNT   12320768
#define WS_TICK  12322816
#define WS_XH    16777216
#define WS_XH_END 83886080

// LDS: A-tile [32 rows][2560B] @0 (80KB, 4-bit row swizzle);
// zbuf [kh4][1024 x 16B] @81920 (64KB, slot16 = (row*32+hcol) ^ (row&7));
// bcast @147456.
#define ZB    81920u
#define BCAST 147456

__device__ __forceinline__ float sigm(float v) { return 1.0f / (1.0f + __expf(-v)); }
__device__ __forceinline__ float tanhfast(float v) {
  float t = __expf(-2.0f * fabsf(v));
  float r = (1.0f - t) / (1.0f + t);
  return v < 0.0f ? -r : r;
}

// ---------- prep: WT[n][k], n=gate*1024+j (z-col), k<1024 -> Wh[k][j], else Wx[k-1024][j]
__global__ __launch_bounds__(256) void prep_wt(
    const float* __restrict__ Wgh, const float* __restrict__ Wih,
    const float* __restrict__ Wfh, const float* __restrict__ Woh,
    const float* __restrict__ Wgx, const float* __restrict__ Wix,
    const float* __restrict__ Wfx, const float* __restrict__ Wox,
    f16* __restrict__ WT)
{
  __shared__ float tile[32][33];
  int bid = blockIdx.x;
  int gate = bid / 1280;
  int rem  = bid % 1280;
  int jt = rem / 40, kt = rem % 40;
  const float* srcH = (gate==0)?Wgh:(gate==1)?Wih:(gate==2)?Wfh:Woh;
  const float* srcX = (gate==0)?Wgx:(gate==1)?Wix:(gate==2)?Wfx:Wox;
  const float* src = (kt < 32) ? (srcH + (size_t)(kt*32)*1024)
                               : (srcX + (size_t)(kt*32 - 1024)*1024);
  int t = threadIdx.x;
  {
    int jl = t & 31, kg = t >> 5;
#pragma unroll
    for (int it = 0; it < 4; ++it) {
      int kl = kg + it*8;
      tile[kl][jl] = src[(size_t)kl*1024 + jt*32 + jl];
    }
  }
  __syncthreads();
  {
    int kl = t & 31, jg = t >> 5;
#pragma unroll
    for (int it = 0; it < 4; ++it) {
      int jl2 = jg + it*8;
      WT[(size_t)(gate*1024 + jt*32 + jl2)*1280 + kt*32 + kl] = (f16)tile[kl][jl2];
    }
  }
}

// ---------- prep: WphT[oc][k] = W_ph[k][oc], fp16
__global__ __launch_bounds__(256) void prep_wph(const float* __restrict__ Wph,
                                                f16* __restrict__ WphT)
{
  __shared__ float tile[32][33];
  int bid = blockIdx.x;
  int jt = bid & 7, kt = bid >> 3;
  int t = threadIdx.x;
  {
    int jl = t & 31, kg = t >> 5;
#pragma unroll
    for (int it = 0; it < 4; ++it) {
      int kl = kg + it*8;
      tile[kl][jl] = Wph[(size_t)(kt*32 + kl)*256 + jt*32 + jl];
    }
  }
  __syncthreads();
  {
    int kl = t & 31, jg = t >> 5;
#pragma unroll
    for (int it = 0; it < 4; ++it) {
      int jl2 = jg + it*8;
      WphT[(size_t)(jt*32 + jl2)*1024 + kt*32 + kl] = (f16)tile[kl][jl2];
    }
  }
}

// ---------- prep: x f32 -> f16 (33.5M elems, 16/thread)
__global__ __launch_bounds__(256) void prep_x16(const float* __restrict__ x,
                                                f16* __restrict__ xh)
{
  size_t i = ((size_t)blockIdx.x*256 + threadIdx.x) * 16;
  const float4* src = (const float4*)(x + i);
  f16x4* dst = (f16x4*)(xh + i);
#pragma unroll
  for (int j = 0; j < 4; ++j) {
    float4 v = src[j];
    f16x4 h; h[0]=(f16)v.x; h[1]=(f16)v.y; h[2]=(f16)v.z; h[3]=(f16)v.w;
    dst[j] = h;
  }
}

// ---------- main persistent LSTM kernel
__global__ __launch_bounds__(512, 2) void lstm_main(
    const float* __restrict__ x, const f16* __restrict__ xh, int use_xh,
    const f16* __restrict__ WT, const f16* __restrict__ WphT,
    f16* __restrict__ hbuf,
    const float* __restrict__ bgp, const float* __restrict__ bip,
    const float* __restrict__ bfp, const float* __restrict__ bop,
    const float* __restrict__ bpp, float* __restrict__ lg,
    u32* __restrict__ cnt, u32* __restrict__ tick, float* __restrict__ out)
{
  __shared__ __align__(16) char smem[147472];
  const int tid  = threadIdx.x;
  const int lane = tid & 63;
  const int wv   = tid >> 6;
  const int hgrp = wv & 1;         // h-col half (16 cols)
  const int kh   = wv >> 1;        // K quarter (320)
  const int l15 = lane & 15, l4 = lane >> 4;

  // ---- measure XCD, take ticket on per-XCD counter
  u32 myxcd;
  asm volatile("s_getreg_b32 %0, hwreg(HW_REG_XCC_ID)" : "=s"(myxcd));
  myxcd &= 7u;
  if (tid == 0) {
    u32 t = __hip_atomic_fetch_add(tick + myxcd, 1u,
                                   __ATOMIC_RELAXED, __HIP_MEMORY_SCOPE_AGENT);
    *(volatile u32*)(smem + BCAST) = t;
  }
  if (wv == 0) {
    u32 v = 0;
    int guard = 0;
    for (;;) {
      v = (lane < 8) ? __hip_atomic_load(tick + lane, __ATOMIC_RELAXED,
                                         __HIP_MEMORY_SCOPE_AGENT) : 0u;
      u32 sum = v;
      sum += __shfl_xor(sum, 1);
      sum += __shfl_xor(sum, 2);
      sum += __shfl_xor(sum, 4);
      if (__shfl(sum, 0) == 256u) break;
      __builtin_amdgcn_s_sleep(1);
      if (++guard > (1 << 20)) break;
    }
    int even = __all((lane < 8) ? (v == 32u) : 1);
    if (lane == 0) *(volatile u32*)(smem + BCAST + 4) = (u32)even;
  }
  __syncthreads();
  const bool xloc = (*(volatile u32*)(smem + BCAST + 4)) != 0u;
  const u32 myticket = *(volatile u32*)(smem + BCAST);
  const int xg = xloc ? (int)myxcd    : (blockIdx.x & 7);   // batch-tile group
  const int cg = xloc ? (int)myticket : (blockIdx.x >> 3);  // column slice 0..31
  u32* flg = cnt + xg*64;           // 32 flags

  // ---- weight-stationary A-op fragments: [10 kk][4 frags] = 160 regs.
  f16x8 Breg[10][4];
  {
    const int gate = l15 & 3, hsub = l15 >> 2;
#pragma unroll
    for (int f = 0; f < 4; ++f) {
      const int n = gate*1024 + cg*32 + hgrp*16 + f*4 + hsub;
      const f16* wb = WT + (size_t)n*1280 + kh*320 + l4*8;
#pragma unroll
      for (int kk = 0; kk < 10; ++kk) {
        Breg[kk][f] = *(const f16x8*)(wb + kk*32);
        asm volatile("" : "+v"(Breg[kk][f]));   // pin: no remat
      }
    }
  }

  // per-thread bias (gates phase handles hcol = tid&31, rows tid>>5 and +16)
  const int bcol = cg*32 + (tid & 31);
  const float bgr = bgp[bcol], bir = bip[bcol], bfr = bfp[bcol], bor = bop[bcol];

  // B-op frag addressing: lane reads rows l15 and l15+16 (same swizzle val)
  const u32 aoff0 = (u32)l15*2560u + (u32)(kh*640 + l4*16);
  const u32 aoff1 = aoff0 + 16u*2560u;
  const u32 aswz  = (u32)l15 << 4;
  // cooperative staging: 32 rows x 16 segs (512 threads), 4-bit swizzle
  const int srow = tid >> 4;       // 0..31
  const int sseg = tid & 15;       // 0..15
  const u32 swzr = ((u32)(srow & 15)) << 4;

  // c state in registers (gates thread owns rows tid>>5 and (tid>>5)+16)
  float c0 = 0.0f, c1 = 0.0f;

  u32 pre = 0xFFFFFFFFu;
  bool preOK = false;

#pragma unroll 1
  for (int s = 0; s < 512; ++s) {
    const int grow = xg*32 + srow;

    // ---- x stage (A-tile x region dead since slot-1's syncB) — pre-spin
    if (use_xh) {
      const char* xrow = (const char*)xh + ((size_t)grow*512 + (size_t)s)*512;
      uint4 v0 = *(const uint4*)(xrow + sseg*16);
      uint4 v1 = *(const uint4*)(xrow + (sseg + 16)*16);
      *(uint4*)(smem + (((u32)srow*2560u + 2048u + (u32)sseg*16u) ^ swzr)) = v0;
      *(uint4*)(smem + (((u32)srow*2560u + 2048u + (u32)(sseg+16)*16u) ^ swzr)) = v1;
    } else {
      const float* xsrc = x + ((size_t)grow*512 + (size_t)s)*256;
#pragma unroll
      for (int j = 0; j < 2; ++j) {
        int cc = sseg + 16*j;
        float4 a = *(const float4*)(xsrc + cc*8);
        float4 b = *(const float4*)(xsrc + cc*8 + 4);
        f16x8 hv;
        hv[0]=(f16)a.x; hv[1]=(f16)a.y; hv[2]=(f16)a.z; hv[3]=(f16)a.w;
        hv[4]=(f16)b.x; hv[5]=(f16)b.y; hv[6]=(f16)b.z; hv[7]=(f16)b.w;
        *(f16x8*)(smem + (((u32)srow*2560u + 2048u + (u32)cc*16u) ^ swzr)) = hv;
      }
    }
    // ---- per-wave barrier: only if this wave's early-poll didn't confirm
    if (s > 0 && !preOK) {
      const u32 tgt = (u32)s;
      u32 v = tgt;
      int guard = 0;
      for (;;) {
        if (lane < 32)
          v = __hip_atomic_load(flg + lane, __ATOMIC_RELAXED,
                                __HIP_MEMORY_SCOPE_AGENT);
        if (__all(v >= tgt)) break;
        __builtin_amdgcn_s_sleep(1);
        if (++guard > (1 << 18)) break;
      }
      if (lane == 0) {
        if (xloc) { asm volatile("buffer_inv sc0\n\ts_waitcnt vmcnt(0)" ::: "memory"); }
        else      { __threadfence(); }
      }
    }
    // ---- cooperative h stage [32 rows x 1024] fp16, XOR-swizzled (4-bit)
    {
      const f16* hsrc = hbuf + (size_t)(s & 1)*262144 + (size_t)grow*1024;
#pragma unroll
      for (int j = 0; j < 8; ++j) {
        int chunk = sseg + 16*j;
        uint4 v = *(const uint4*)(hsrc + chunk*8);
        *(uint4*)(smem + (((u32)srow*2560u + 16u*(u32)chunk) ^ swzr)) = v;
      }
    }
    __syncthreads();   // (A) staging complete
    // ---- K loop: K/4 per wave; rows 0-15 (av0) and 16-31 (av1)
    f32x4 a00 = {}, a01 = {}, a02 = {}, a03 = {};
    f32x4 a10 = {}, a11 = {}, a12 = {}, a13 = {};
#pragma unroll
    for (int kk = 0; kk < 10; ++kk) {
      f16x8 av0 = *(const f16x8*)(smem + ((aoff0 + (u32)kk*64u) ^ aswz));
      f16x8 av1 = *(const f16x8*)(smem + ((aoff1 + (u32)kk*64u) ^ aswz));
      a00 = __builtin_amdgcn_mfma_f32_16x16x32_f16(Breg[kk][0], av0, a00, 0, 0, 0);
      a01 = __builtin_amdgcn_mfma_f32_16x16x32_f16(Breg[kk][1], av0, a01, 0, 0, 0);
      a02 = __builtin_amdgcn_mfma_f32_16x16x32_f16(Breg[kk][2], av0, a02, 0, 0, 0);
      a03 = __builtin_amdgcn_mfma_f32_16x16x32_f16(Breg[kk][3], av0, a03, 0, 0, 0);
      a10 = __builtin_amdgcn_mfma_f32_16x16x32_f16(Breg[kk][0], av1, a10, 0, 0, 0);
      a11 = __builtin_amdgcn_mfma_f32_16x16x32_f16(Breg[kk][1], av1, a11, 0, 0, 0);
      a12 = __builtin_amdgcn_mfma_f32_16x16x32_f16(Breg[kk][2], av1, a12, 0, 0, 0);
      a13 = __builtin_amdgcn_mfma_f32_16x16x32_f16(Breg[kk][3], av1, a13, 0, 0, 0);
    }
    // ---- early poll (ALL waves): next step's flags, consumed after gates
    {
      const int nS = s + 1;
      pre = 0xFFFFFFFFu;
      if (nS < 512 && lane < 32)
        pre = __hip_atomic_load(flg + lane, __ATOMIC_RELAXED,
                                __HIP_MEMORY_SCOPE_AGENT);
    }
    // ---- zbuf partial write: f32x4 at slot16 = (row*32+hcol) ^ (row&7)
    {
      const u32 zkh = ZB + (u32)kh*16384u;
#pragma unroll
      for (int f = 0; f < 4; ++f) {
        const u32 hcol = (u32)(hgrp*16 + f*4 + l4);
        const u32 r0 = (u32)l15, r1 = (u32)(l15 + 16);
        const u32 s0 = ((r0*32u) + hcol) ^ (r0 & 7u);
        const u32 s1 = ((r1*32u) + hcol) ^ (r1 & 7u);
        f32x4 p0 = (f==0)?a00:(f==1)?a01:(f==2)?a02:a03;
        f32x4 p1 = (f==0)?a10:(f==1)?a11:(f==2)?a12:a13;
        *(f32x4*)(smem + zkh + s0*16u) = p0;
        *(f32x4*)(smem + zkh + s1*16u) = p1;
      }
    }
    __syncthreads();   // (B) zbuf ready
    // ---- gates: thread owns (rows tid>>5 and +16, hcol=tid&31)
    {
      f16* hw = hbuf + (size_t)((s & 1) ^ 1)*262144;
      const int hcol = tid & 31;
#pragma unroll
      for (int e2 = 0; e2 < 2; ++e2) {
        const int row = (tid >> 5) + e2*16;
        const u32 s16 = ((u32)(row*32) + (u32)hcol) ^ ((u32)(row & 7));
        const u32 ro = s16*16u;
        f32x4 z0 = *(const f32x4*)(smem + ZB +          ro);
        f32x4 z1 = *(const f32x4*)(smem + ZB + 16384u + ro);
        f32x4 z2 = *(const f32x4*)(smem + ZB + 32768u + ro);
        f32x4 z3 = *(const f32x4*)(smem + ZB + 49152u + ro);
        float zg = z0[0] + z1[0] + z2[0] + z3[0] + bgr;
        float zi = z0[1] + z1[1] + z2[1] + z3[1] + bir;
        float zf = z0[2] + z1[2] + z2[2] + z3[2] + bfr;
        float zo = z0[3] + z1[3] + z2[3] + z3[3] + bor;
        float cv = e2 ? c1 : c0;
        float gv = tanhfast(zg);
        float iv = sigm(zi);
        float fv = sigm(zf);
        float ov = sigm(zo);
        float cn = gv*iv + cv*fv;
        if (e2) c1 = cn; else c0 = cn;
        hw[(size_t)(xg*32 + row)*1024 + cg*32 + hcol] = (f16)(tanhfast(cn) * ov);
      }
    }
    // ---- preOK eval + deferred inv (per wave)
    {
      const int nS = s + 1;
      bool ok = (nS >= 512) || __all(pre >= (u32)nS);
      preOK = xloc && ok;
      if (preOK && nS < 512 && lane == 0) {
        asm volatile("buffer_inv sc0\n\ts_waitcnt vmcnt(0)" ::: "memory");
      }
    }
    __syncthreads();   // (C) drains h stores + orders inv before next slot
    if (tid == 0) {
      if (!xloc) __threadfence();
      __hip_atomic_store(flg + cg, (u32)(s + 1),
                         __ATOMIC_RELAXED, __HIP_MEMORY_SCOPE_AGENT);
    }
  }

  // ---- epilogue: wait group at 512, logits = h @ WphT + bp
  if (wv == 0) {
    u32 v = 512u;
    int guard = 0;
    for (;;) {
      if (lane < 32)
        v = __hip_atomic_load(flg + lane, __ATOMIC_RELAXED,
                              __HIP_MEMORY_SCOPE_AGENT);
      if (__all(v >= 512u)) break;
      __builtin_amdgcn_s_sleep(1);
      if (++guard > (1 << 18)) break;
    }
    if (lane == 0) {
      if (xloc) { asm volatile("buffer_inv sc0\n\ts_waitcnt vmcnt(0)" ::: "memory"); }
      else      { __threadfence(); }
    }
  }
  __syncthreads();
  {
#pragma unroll 1
    for (int p = 0; p < 32; ++p) {
      int rowl = wv*4 + (p >> 3);
      int oc   = p & 7;
      const f16* hp = hbuf + (size_t)(xg*32 + rowl)*1024 + lane*16;  // buf 0 = h_T
      const f16* wp = WphT + (size_t)(cg*8 + oc)*1024 + lane*16;
      f16x8 h0 = *(const f16x8*)hp;
      f16x8 h1 = *(const f16x8*)(hp + 8);
      f16x8 w0 = *(const f16x8*)wp;
      f16x8 w1 = *(const f16x8*)(wp + 8);
      float sum = 0.f;
#pragma unroll
      for (int q = 0; q < 8; ++q)
        sum += (float)h0[q]*(float)w0[q] + (float)h1[q]*(float)w1[q];
#pragma unroll
      for (int d = 1; d < 64; d <<= 1) sum += __shfl_xor(sum, d);
      if (lane == 0)
        lg[(size_t)(xg*32 + rowl)*256 + cg*8 + oc] = sum + bpp[cg*8 + oc];
    }
  }
  __syncthreads();   // drain lg stores
  if (tid == 0) {
    if (!xloc) __threadfence();
    __hip_atomic_store(flg + cg, 513u, __ATOMIC_RELAXED, __HIP_MEMORY_SCOPE_AGENT);
  }
  if (wv == 0) {
    u32 v = 513u;
    int guard = 0;
    for (;;) {
      if (lane < 32)
        v = __hip_atomic_load(flg + lane, __ATOMIC_RELAXED, __HIP_MEMORY_SCOPE_AGENT);
      if (__all(v >= 513u)) break;
      __builtin_amdgcn_s_sleep(1);
      if (++guard > (1 << 18)) break;
    }
    if (lane == 0) {
      if (xloc) { asm volatile("buffer_inv sc0\n\ts_waitcnt vmcnt(0)" ::: "memory"); }
      else      { __threadfence(); }
    }
  }
  __syncthreads();
  // ---- softmax: this block handles row xg*32+cg, wave 0 only
  if (tid < 64) {
    int rowg = xg*32 + cg;
    const float* lr = lg + (size_t)rowg*256;
    float v0 = lr[tid], v1 = lr[tid+64], v2 = lr[tid+128], v3 = lr[tid+192];
    float mx = fmaxf(fmaxf(v0, v1), fmaxf(v2, v3));
#pragma unroll
    for (int d = 1; d < 64; d <<= 1) mx = fmaxf(mx, __shfl_xor(mx, d));
    float e0 = __expf(v0-mx), e1 = __expf(v1-mx), e2 = __expf(v2-mx), e3 = __expf(v3-mx);
    float sm = e0+e1+e2+e3;
#pragma unroll
    for (int d = 1; d < 64; d <<= 1) sm += __shfl_xor(sm, d);
    float inv = 1.0f / sm;
    float* orow = out + (size_t)rowg*256;
    orow[tid]      = e0*inv;
    orow[tid+64]   = e1*inv;
    orow[tid+128]  = e2*inv;
    orow[tid+192]  = e3*inv;
  }
}

extern "C" void kernel_launch(void* const* d_in, const int* in_sizes, int n_in,
                              void* d_out, int out_size, void* d_ws, size_t ws_size,
                              hipStream_t stream) {
  (void)in_sizes; (void)n_in; (void)out_size;
  const float* x   = (const float*)d_in[0];
  const float* Wgx = (const float*)d_in[1];
  const float* Wgh = (const float*)d_in[2];
  const float* bg  = (const float*)d_in[3];
  const float* Wix = (const float*)d_in[4];
  const float* Wih = (const float*)d_in[5];
  const float* bi  = (const float*)d_in[6];
  const float* Wfx = (const float*)d_in[7];
  const float* Wfh = (const float*)d_in[8];
  const float* bf  = (const float*)d_in[9];
  const float* Wox = (const float*)d_in[10];
  const float* Woh = (const float*)d_in[11];
  const float* bo  = (const float*)d_in[12];
  const float* Wph = (const float*)d_in[13];
  const float* bp  = (const float*)d_in[14];

  char* ws = (char*)d_ws;
  f16*   WT   = (f16*)(ws + WS_WT);
  f16*   WphT = (f16*)(ws + WS_WPHT);
  f16*   hbuf = (f16*)(ws + WS_HBUF);
  float* lg   = (float*)(ws + WS_LG);
  u32*   cnt  = (u32*)(ws + WS_CNT);
  u32*   tick = (u32*)(ws + WS_TICK);
  const int use_xh = (ws_size >= (size_t)WS_XH_END) ? 1 : 0;
  f16*   xh   = (f16*)(ws + WS_XH);

  // h0 = 0 (buffer 0); flags + tickets = 0 (replay-safe)
  hipMemsetAsync(hbuf, 0, 524288, stream);
  hipMemsetAsync(cnt, 0, 2048 + 64, stream);

  prep_wt<<<5120, 256, 0, stream>>>(Wgh, Wih, Wfh, Woh, Wgx, Wix, Wfx, Wox, WT);
  prep_wph<<<256, 256, 0, stream>>>(Wph, WphT);
  if (use_xh)
    prep_x16<<<8192, 256, 0, stream>>>(x, xh);
  lstm_main<<<256, 512, 0, stream>>>(x, xh, use_xh, WT, WphT, hbuf,
                                     bg, bi, bf, bo, bp,
                                     lg, cnt, tick, (float*)d_out);
}

// Round 18
// 2463.684 us; speedup vs baseline: 1.5053x; 1.1346x over previous
//
#include <hip/hip_runtime.h>

// LSTM fused kernel for MI355X (gfx950) — FINAL (= round 15, best: 2472us).
// All structural neighbors measured worse: per-wave staging (r13 +84%),
// ticket slot-end (r14 +5%), direct-L2 operands (r16 +50%), un-interleaved
// slots (r17 +13%, L2 writeback storm). This configuration is the optimum:
// 256 blocks x 512 threads (8 waves, 2/SIMD). Group = measured XCD; 32 batch
// rows split into tiles A/B (16 rows) alternated per slot (hides flag
// latency AND keeps h L2-resident).
// Transposed MFMA: wave (hgrp=wv&1, kh=wv>>1), z^T = W·[h|x]^T, lane holds
// all 4 gates of one (row,hcol); cross-kh reduce via single 32KB zbuf;
// c in regs; gates all-lanes. 3 syncthreads/slot (A: stage, B: zbuf, C: end).
// Sync: relaxed agent flags + per-wave buffer_inv sc0 acquire, early-poll,
// deferred inv; threadfence fallback; guards 1<<18.
// Workspace: WT fp16 [4096][1280] @0, WphT @10485760,
// hbuf [2][256][1024] @11010048, lg @12058624, cnt @12320768, tick @12322816,
// xh fp16 [256][512][256] @16777216 (only if ws_size >= 83886080).

typedef _Float16 f16;
typedef _Float16 f16x8 __attribute__((ext_vector_type(8)));
typedef _Float16 f16x4 __attribute__((ext_vector_type(4)));
typedef float f32x4 __attribute__((ext_vector_type(4)));
typedef unsigned int u32;

#define WS_WT    0
#define WS_WPHT  10485760
#define WS_HBUF  11010048
#define WS_LG    12058624
#define WS_CNT   12320768
#define WS_TICK  12322816
#define WS_XH    16777216
#define WS_XH_END 83886080

// LDS: A-tile[2] [16 rows][2560B] @0/@40960 (4-bit row swizzle);
// zbuf [kh4][512 x 16B] @81920 (32 KB, slot16 = (row*32+hcol) ^ (row&7));
// bcast @114688.
#define ZB    81920u
#define BCAST 114688

__device__ __forceinline__ float sigm(float v) { return 1.0f / (1.0f + __expf(-v)); }
__device__ __forceinline__ float tanhfast(float v) {
  float t = __expf(-2.0f * fabsf(v));
  float r = (1.0f - t) / (1.0f + t);
  return v < 0.0f ? -r : r;
}

// ---------- prep: WT[n][k], n=gate*1024+j (z-col), k<1024 -> Wh[k][j], else Wx[k-1024][j]
__global__ __launch_bounds__(256) void prep_wt(
    const float* __restrict__ Wgh, const float* __restrict__ Wih,
    const float* __restrict__ Wfh, const float* __restrict__ Woh,
    const float* __restrict__ Wgx, const float* __restrict__ Wix,
    const float* __restrict__ Wfx, const float* __restrict__ Wox,
    f16* __restrict__ WT)
{
  __shared__ float tile[32][33];
  int bid = blockIdx.x;
  int gate = bid / 1280;
  int rem  = bid % 1280;
  int jt = rem / 40, kt = rem % 40;
  const float* srcH = (gate==0)?Wgh:(gate==1)?Wih:(gate==2)?Wfh:Woh;
  const float* srcX = (gate==0)?Wgx:(gate==1)?Wix:(gate==2)?Wfx:Wox;
  const float* src = (kt < 32) ? (srcH + (size_t)(kt*32)*1024)
                               : (srcX + (size_t)(kt*32 - 1024)*1024);
  int t = threadIdx.x;
  {
    int jl = t & 31, kg = t >> 5;
#pragma unroll
    for (int it = 0; it < 4; ++it) {
      int kl = kg + it*8;
      tile[kl][jl] = src[(size_t)kl*1024 + jt*32 + jl];
    }
  }
  __syncthreads();
  {
    int kl = t & 31, jg = t >> 5;
#pragma unroll
    for (int it = 0; it < 4; ++it) {
      int jl2 = jg + it*8;
      WT[(size_t)(gate*1024 + jt*32 + jl2)*1280 + kt*32 + kl] = (f16)tile[kl][jl2];
    }
  }
}

// ---------- prep: WphT[oc][k] = W_ph[k][oc], fp16
__global__ __launch_bounds__(256) void prep_wph(const float* __restrict__ Wph,
                                                f16* __restrict__ WphT)
{
  __shared__ float tile[32][33];
  int bid = blockIdx.x;
  int jt = bid & 7, kt = bid >> 3;
  int t = threadIdx.x;
  {
    int jl = t & 31, kg = t >> 5;
#pragma unroll
    for (int it = 0; it < 4; ++it) {
      int kl = kg + it*8;
      tile[kl][jl] = Wph[(size_t)(kt*32 + kl)*256 + jt*32 + jl];
    }
  }
  __syncthreads();
  {
    int kl = t & 31, jg = t >> 5;
#pragma unroll
    for (int it = 0; it < 4; ++it) {
      int jl2 = jg + it*8;
      WphT[(size_t)(jt*32 + jl2)*1024 + kt*32 + kl] = (f16)tile[kl][jl2];
    }
  }
}

// ---------- prep: x f32 -> f16 (33.5M elems, 16/thread)
__global__ __launch_bounds__(256) void prep_x16(const float* __restrict__ x,
                                                f16* __restrict__ xh)
{
  size_t i = ((size_t)blockIdx.x*256 + threadIdx.x) * 16;
  const float4* src = (const float4*)(x + i);
  f16x4* dst = (f16x4*)(xh + i);
#pragma unroll
  for (int j = 0; j < 4; ++j) {
    float4 v = src[j];
    f16x4 h; h[0]=(f16)v.x; h[1]=(f16)v.y; h[2]=(f16)v.z; h[3]=(f16)v.w;
    dst[j] = h;
  }
}

// ---------- main persistent LSTM kernel
__global__ __launch_bounds__(512, 2) void lstm_main(
    const float* __restrict__ x, const f16* __restrict__ xh, int use_xh,
    const f16* __restrict__ WT, const f16* __restrict__ WphT,
    f16* __restrict__ hbuf,
    const float* __restrict__ bgp, const float* __restrict__ bip,
    const float* __restrict__ bfp, const float* __restrict__ bop,
    const float* __restrict__ bpp, float* __restrict__ lg,
    u32* __restrict__ cnt, u32* __restrict__ tick, float* __restrict__ out)
{
  __shared__ __align__(16) char smem[114704];
  const int tid  = threadIdx.x;
  const int lane = tid & 63;
  const int wv   = tid >> 6;
  const int hgrp = wv & 1;         // h-col half (16 cols)
  const int kh   = wv >> 1;        // K quarter (320)
  const int l15 = lane & 15, l4 = lane >> 4;

  // ---- measure XCD, take ticket on per-XCD counter
  u32 myxcd;
  asm volatile("s_getreg_b32 %0, hwreg(HW_REG_XCC_ID)" : "=s"(myxcd));
  myxcd &= 7u;
  if (tid == 0) {
    u32 t = __hip_atomic_fetch_add(tick + myxcd, 1u,
                                   __ATOMIC_RELAXED, __HIP_MEMORY_SCOPE_AGENT);
    *(volatile u32*)(smem + BCAST) = t;
  }
  if (wv == 0) {
    u32 v = 0;
    int guard = 0;
    for (;;) {
      v = (lane < 8) ? __hip_atomic_load(tick + lane, __ATOMIC_RELAXED,
                                         __HIP_MEMORY_SCOPE_AGENT) : 0u;
      u32 sum = v;
      sum += __shfl_xor(sum, 1);
      sum += __shfl_xor(sum, 2);
      sum += __shfl_xor(sum, 4);
      if (__shfl(sum, 0) == 256u) break;
      __builtin_amdgcn_s_sleep(1);
      if (++guard > (1 << 20)) break;
    }
    int even = __all((lane < 8) ? (v == 32u) : 1);
    if (lane == 0) *(volatile u32*)(smem + BCAST + 4) = (u32)even;
  }
  __syncthreads();
  const bool xloc = (*(volatile u32*)(smem + BCAST + 4)) != 0u;
  const u32 myticket = *(volatile u32*)(smem + BCAST);
  const int xg = xloc ? (int)myxcd    : (blockIdx.x & 7);   // batch-tile group
  const int cg = xloc ? (int)myticket : (blockIdx.x >> 3);  // column slice 0..31
  u32* flg = cnt + xg*64;           // [tileA flags 0..31][tileB flags 32..63]

  // ---- weight-stationary A-op fragments: [10 kk][4 frags] = 160 regs.
  // Lane l15 = m = hcolsub*4 + gate (gate-minor interleave).
  f16x8 Breg[10][4];
  {
    const int gate = l15 & 3, hsub = l15 >> 2;
#pragma unroll
    for (int f = 0; f < 4; ++f) {
      const int n = gate*1024 + cg*32 + hgrp*16 + f*4 + hsub;
      const f16* wb = WT + (size_t)n*1280 + kh*320 + l4*8;
#pragma unroll
      for (int kk = 0; kk < 10; ++kk) {
        Breg[kk][f] = *(const f16x8*)(wb + kk*32);
        asm volatile("" : "+v"(Breg[kk][f]));   // pin: no remat
      }
    }
  }

  // per-thread bias (gates phase handles hcol = tid&31)
  const int bcol = cg*32 + (tid & 31);
  const float bgr = bgp[bcol], bir = bip[bcol], bfr = bfp[bcol], bor = bop[bcol];

  // B-op (activations) frag addressing: lane l15 = batch row
  const u32 aoff = (u32)l15*2560u + (u32)(kh*640 + l4*16);
  const u32 aswz = (u32)l15 << 4;
  // cooperative staging: 16 rows x 32 segs (512 threads), 4-bit swizzle
  const int srow = tid >> 5;
  const int sseg = tid & 31;
  const u32 swzr = (u32)srow << 4;

  // c state in registers (gates thread owns (row=tid>>5, hcol=tid&31))
  float cA = 0.0f, cB = 0.0f;

  u32 pre = 0xFFFFFFFFu;
  bool preOK = false;

#pragma unroll 1
  for (int slot = 0; slot < 1024; ++slot) {
    const int T = slot & 1, s = slot >> 1;
    const u32 Abase = (u32)T * 40960u;
    u32* flgT = flg + T*32;
    const int grow = xg*32 + T*16 + srow;

    // ---- x stage (tile-T x region dead since slot-2) — overlaps flag latency
    if (use_xh) {
      const char* xrow = (const char*)xh + ((size_t)grow*512 + (size_t)s)*512;
      uint4 v = *(const uint4*)(xrow + sseg*16);
      *(uint4*)(smem + Abase + (((u32)srow*2560u + 2048u + (u32)sseg*16u) ^ swzr)) = v;
    } else {
      const float* xsrc = x + ((size_t)grow*512 + (size_t)s)*256;
      float4 xv0 = *(const float4*)(xsrc + (sseg     )*4);
      float4 xv1 = *(const float4*)(xsrc + (sseg + 32)*4);
      f16x4 hv;
      hv[0] = (f16)xv0.x; hv[1] = (f16)xv0.y; hv[2] = (f16)xv0.z; hv[3] = (f16)xv0.w;
      *(f16x4*)(smem + Abase + (((u32)srow*2560u + 2048u + 8u*(u32)(sseg     )) ^ swzr)) = hv;
      hv[0] = (f16)xv1.x; hv[1] = (f16)xv1.y; hv[2] = (f16)xv1.z; hv[3] = (f16)xv1.w;
      *(f16x4*)(smem + Abase + (((u32)srow*2560u + 2048u + 8u*(u32)(sseg + 32)) ^ swzr)) = hv;
    }
    // ---- per-wave barrier: only if this wave's early-poll didn't confirm
    if (s > 0 && !preOK) {
      const u32 tgt = (u32)s;
      u32 v = tgt;
      int guard = 0;
      for (;;) {
        if (lane < 32)
          v = __hip_atomic_load(flgT + lane, __ATOMIC_RELAXED,
                                __HIP_MEMORY_SCOPE_AGENT);
        if (__all(v >= tgt)) break;
        __builtin_amdgcn_s_sleep(1);
        if (++guard > (1 << 18)) break;
      }
      if (lane == 0) {
        if (xloc) { asm volatile("buffer_inv sc0\n\ts_waitcnt vmcnt(0)" ::: "memory"); }
        else      { __threadfence(); }
      }
    }
    // ---- cooperative h stage [16 rows x 1024] fp16, XOR-swizzled
    {
      const f16* hsrc = hbuf + (size_t)(s & 1)*262144 + (size_t)grow*1024;
#pragma unroll
      for (int j = 0; j < 4; ++j) {
        int chunk = sseg + 32*j;
        uint4 v = *(const uint4*)(hsrc + chunk*8);
        *(uint4*)(smem + Abase + (((u32)srow*2560u + 16u*(u32)chunk) ^ swzr)) = v;
      }
    }
    __syncthreads();   // (A) staging complete
    // ---- K loop: K/4 per wave; one av feeds 4 col-frags (gates in lanes)
    f32x4 acc0 = {}, acc1 = {}, acc2 = {}, acc3 = {};
#pragma unroll
    for (int kk = 0; kk < 10; ++kk) {
      f16x8 av = *(const f16x8*)(smem + Abase + ((aoff + (u32)kk*64u) ^ aswz));
      acc0 = __builtin_amdgcn_mfma_f32_16x16x32_f16(Breg[kk][0], av, acc0, 0, 0, 0);
      acc1 = __builtin_amdgcn_mfma_f32_16x16x32_f16(Breg[kk][1], av, acc1, 0, 0, 0);
      acc2 = __builtin_amdgcn_mfma_f32_16x16x32_f16(Breg[kk][2], av, acc2, 0, 0, 0);
      acc3 = __builtin_amdgcn_mfma_f32_16x16x32_f16(Breg[kk][3], av, acc3, 0, 0, 0);
    }
    // ---- early poll (ALL waves): next slot's flags, consumed after gates
    {
      const int nT = (slot + 1) & 1, nS = (slot + 1) >> 1;
      pre = 0xFFFFFFFFu;
      if (nS > 0 && nS < 512 && lane < 32)
        pre = __hip_atomic_load(flg + nT*32 + lane, __ATOMIC_RELAXED,
                                __HIP_MEMORY_SCOPE_AGENT);
    }
    // ---- zbuf partial write: f32x4 (4 gates) at slot16=(row*32+hcol)^(row&7)
    {
      const u32 zkh = ZB + (u32)kh*8192u;
#pragma unroll
      for (int f = 0; f < 4; ++f) {
        const u32 hcol = (u32)(hgrp*16 + f*4 + l4);
        const u32 s16 = ((u32)(l15*32) + hcol) ^ ((u32)(l15 & 7));
        f32x4 acc = (f==0)?acc0:(f==1)?acc1:(f==2)?acc2:acc3;
        *(f32x4*)(smem + zkh + s16*16u) = acc;
      }
    }
    __syncthreads();   // (B) zbuf ready
    // ---- gates: thread (row=tid>>5, hcol=tid&31), all lanes active
    {
      f16* hw = hbuf + (size_t)((s & 1) ^ 1)*262144;
      const int row = tid >> 5, hcol = tid & 31;
      const u32 s16 = ((u32)(row*32) + (u32)hcol) ^ ((u32)(row & 7));
      const u32 ro = s16*16u;
      f32x4 z0 = *(const f32x4*)(smem + ZB +        ro);
      f32x4 z1 = *(const f32x4*)(smem + ZB + 8192u  + ro);
      f32x4 z2 = *(const f32x4*)(smem + ZB + 16384u + ro);
      f32x4 z3 = *(const f32x4*)(smem + ZB + 24576u + ro);
      float zg = z0[0] + z1[0] + z2[0] + z3[0] + bgr;
      float zi = z0[1] + z1[1] + z2[1] + z3[1] + bir;
      float zf = z0[2] + z1[2] + z2[2] + z3[2] + bfr;
      float zo = z0[3] + z1[3] + z2[3] + z3[3] + bor;
      float cv = T ? cB : cA;
      float gv = tanhfast(zg);
      float iv = sigm(zi);
      float fv = sigm(zf);
      float ov = sigm(zo);
      float cn = gv*iv + cv*fv;
      if (T) cB = cn; else cA = cn;
      hw[(size_t)(xg*32 + T*16 + row)*1024 + cg*32 + hcol] = (f16)(tanhfast(cn) * ov);
    }
    // ---- preOK eval + deferred inv (per wave)
    {
      const int nS = (slot + 1) >> 1;
      bool ok = (nS >= 512) || __all(pre >= (u32)nS);
      preOK = xloc && ok;
      if (preOK && nS < 512 && lane == 0) {
        asm volatile("buffer_inv sc0\n\ts_waitcnt vmcnt(0)" ::: "memory");
      }
    }
    __syncthreads();   // (C) drains h stores + orders inv before next slot
    if (tid == 0) {
      if (!xloc) __threadfence();
      __hip_atomic_store(flgT + cg, (u32)(s + 1),
                         __ATOMIC_RELAXED, __HIP_MEMORY_SCOPE_AGENT);
    }
  }

  // ---- epilogue: wait both tiles at 512, logits = h @ WphT + bp
  if (wv == 0) {
    u32 v = 512u;
    int guard = 0;
    for (;;) {
      v = __hip_atomic_load(flg + lane, __ATOMIC_RELAXED,
                            __HIP_MEMORY_SCOPE_AGENT);   // lanes 0-63 = A,B
      if (__all(v >= 512u)) break;
      __builtin_amdgcn_s_sleep(1);
      if (++guard > (1 << 18)) break;
    }
    if (lane == 0) {
      if (xloc) { asm volatile("buffer_inv sc0\n\ts_waitcnt vmcnt(0)" ::: "memory"); }
      else      { __threadfence(); }
    }
  }
  __syncthreads();
  {
#pragma unroll 1
    for (int p = 0; p < 32; ++p) {
      int rowl = wv*4 + (p >> 3);
      int oc   = p & 7;
      const f16* hp = hbuf + (size_t)(xg*32 + rowl)*1024 + lane*16;  // buf 0 = h_T
      const f16* wp = WphT + (size_t)(cg*8 + oc)*1024 + lane*16;
      f16x8 h0 = *(const f16x8*)hp;
      f16x8 h1 = *(const f16x8*)(hp + 8);
      f16x8 w0 = *(const f16x8*)wp;
      f16x8 w1 = *(const f16x8*)(wp + 8);
      float sum = 0.f;
#pragma unroll
      for (int q = 0; q < 8; ++q)
        sum += (float)h0[q]*(float)w0[q] + (float)h1[q]*(float)w1[q];
#pragma unroll
      for (int d = 1; d < 64; d <<= 1) sum += __shfl_xor(sum, d);
      if (lane == 0)
        lg[(size_t)(xg*32 + rowl)*256 + cg*8 + oc] = sum + bpp[cg*8 + oc];
    }
  }
  __syncthreads();   // drain lg stores
  if (tid == 0) {
    if (!xloc) __threadfence();
    __hip_atomic_store(flg + cg, 513u, __ATOMIC_RELAXED, __HIP_MEMORY_SCOPE_AGENT);
  }
  if (wv == 0) {
    u32 v = 513u;
    int guard = 0;
    for (;;) {
      if (lane < 32)
        v = __hip_atomic_load(flg + lane, __ATOMIC_RELAXED, __HIP_MEMORY_SCOPE_AGENT);
      if (__all(v >= 513u)) break;
      __builtin_amdgcn_s_sleep(1);
      if (++guard > (1 << 18)) break;
    }
    if (lane == 0) {
      if (xloc) { asm volatile("buffer_inv sc0\n\ts_waitcnt vmcnt(0)" ::: "memory"); }
      else      { __threadfence(); }
    }
  }
  __syncthreads();
  // ---- softmax: this block handles row xg*32+cg, wave 0 only
  if (tid < 64) {
    int rowg = xg*32 + cg;
    const float* lr = lg + (size_t)rowg*256;
    float v0 = lr[tid], v1 = lr[tid+64], v2 = lr[tid+128], v3 = lr[tid+192];
    float mx = fmaxf(fmaxf(v0, v1), fmaxf(v2, v3));
#pragma unroll
    for (int d = 1; d < 64; d <<= 1) mx = fmaxf(mx, __shfl_xor(mx, d));
    float e0 = __expf(v0-mx), e1 = __expf(v1-mx), e2 = __expf(v2-mx), e3 = __expf(v3-mx);
    float sm = e0+e1+e2+e3;
#pragma unroll
    for (int d = 1; d < 64; d <<= 1) sm += __shfl_xor(sm, d);
    float inv = 1.0f / sm;
    float* orow = out + (size_t)rowg*256;
    orow[tid]      = e0*inv;
    orow[tid+64]   = e1*inv;
    orow[tid+128]  = e2*inv;
    orow[tid+192]  = e3*inv;
  }
}

extern "C" void kernel_launch(void* const* d_in, const int* in_sizes, int n_in,
                              void* d_out, int out_size, void* d_ws, size_t ws_size,
                              hipStream_t stream) {
  (void)in_sizes; (void)n_in; (void)out_size;
  const float* x   = (const float*)d_in[0];
  const float* Wgx = (const float*)d_in[1];
  const float* Wgh = (const float*)d_in[2];
  const float* bg  = (const float*)d_in[3];
  const float* Wix = (const float*)d_in[4];
  const float* Wih = (const float*)d_in[5];
  const float* bi  = (const float*)d_in[6];
  const float* Wfx = (const float*)d_in[7];
  const float* Wfh = (const float*)d_in[8];
  const float* bf  = (const float*)d_in[9];
  const float* Wox = (const float*)d_in[10];
  const float* Woh = (const float*)d_in[11];
  const float* bo  = (const float*)d_in[12];
  const float* Wph = (const float*)d_in[13];
  const float* bp  = (const float*)d_in[14];

  char* ws = (char*)d_ws;
  f16*   WT   = (f16*)(ws + WS_WT);
  f16*   WphT = (f16*)(ws + WS_WPHT);
  f16*   hbuf = (f16*)(ws + WS_HBUF);
  float* lg   = (float*)(ws + WS_LG);
  u32*   cnt  = (u32*)(ws + WS_CNT);
  u32*   tick = (u32*)(ws + WS_TICK);
  const int use_xh = (ws_size >= (size_t)WS_XH_END) ? 1 : 0;
  f16*   xh   = (f16*)(ws + WS_XH);

  // h0 = 0 (buffer 0); flags + tickets = 0 (replay-safe)
  hipMemsetAsync(hbuf, 0, 524288, stream);
  hipMemsetAsync(cnt, 0, 2048 + 64, stream);

  prep_wt<<<5120, 256, 0, stream>>>(Wgh, Wih, Wfh, Woh, Wgx, Wix, Wfx, Wox, WT);
  prep_wph<<<256, 256, 0, stream>>>(Wph, WphT);
  if (use_xh)
    prep_x16<<<8192, 256, 0, stream>>>(x, xh);
  lstm_main<<<256, 512, 0, stream>>>(x, xh, use_xh, WT, WphT, hbuf,
                                     bg, bi, bf, bo, bp,
                                     lg, cnt, tick, (float*)d_out);
}